// Round 1
// 1255.082 us; speedup vs baseline: 1.0064x; 1.0064x over previous
//
#include <hip/hip_runtime.h>

#define Bn 64
#define Tn 1024
#define Cn 256
#define TCROWS 127  // transT rows cached in bwd LDS (127KB + 32KB ring + tags < 160KB)

// Native clang vector for nontemporal builtins (HIP float4 is a class type).
typedef float nv4 __attribute__((ext_vector_type(4)));
__device__ __forceinline__ float4 nt_load4(const float* p) {
  nv4 r = __builtin_nontemporal_load((const nv4*)p);
  return make_float4(r.x, r.y, r.z, r.w);
}
__device__ __forceinline__ void nt_store4(float* p, float4 v) {
  nv4 r = {v.x, v.y, v.z, v.w};
  __builtin_nontemporal_store(r, (nv4*)p);
}

// Single-instruction 3-input max (gfx9+). Exact: fp32 max is associative.
__device__ __forceinline__ float max3f(float a, float b, float c) {
  float d;
  asm("v_max3_f32 %0, %1, %2, %3" : "=v"(d) : "v"(a), "v"(b), "v"(c));
  return d;
}

// ---------------- DPP helpers ----------------
template<int CTRL>
__device__ __forceinline__ float dpp_mov_f(float x) {
  return __int_as_float(__builtin_amdgcn_update_dpp(0, __float_as_int(x), CTRL, 0xF, 0xF, true));
}
template<int CTRL>
__device__ __forceinline__ void max_stage(float& v) {
  const float pv = __int_as_float(__builtin_amdgcn_update_dpp(
      (int)0xFF800000, __float_as_int(v), CTRL, 0xF, 0xF, false));
  v = fmaxf(v, pv);
}

// Fast 64-lane argmax (min index on ties). Matches jnp argmax tie-break.
__device__ __forceinline__ int argmax64_fast(float v, int i) {
  float mv = v;
  max_stage<0x111>(mv);  // row_shr:1
  max_stage<0x112>(mv);  // row_shr:2
  max_stage<0x114>(mv);  // row_shr:4
  max_stage<0x118>(mv);  // row_shr:8
  max_stage<0x142>(mv);  // row_bcast15
  max_stage<0x143>(mv);  // row_bcast31  -> lane 63 has global max
  const float smax = __int_as_float(__builtin_amdgcn_readlane(__float_as_int(mv), 63));
  const unsigned long long m = __ballot(v == smax);
  const int ln = __ffsll((unsigned long long)m) - 1;
  return __builtin_amdgcn_readlane(i, ln);
}

// Padded alpha LDS layout (R3-verified: conflicts 5.0e7 -> 512):
// chunk m at float offset (m>>2)*20 + (m&3)*4. Buffer = 320 floats.
__device__ __forceinline__ int apad(int m) { return (m >> 2) * 20 + (m & 3) * 4; }

// Reduce 16 cp cells into accumulator M for one cc component CMP.
// 16 v_add + 1 v_max + 7 v_max3 = 24 instrs (was 32 add/max + init/combine).
// Chain depth 8 (same as the old split-halves scheme); exact (max associative).
#define REDUCE_CC(M, CMP)                                                     \
  {                                                                           \
    M = fmaxf(a0.x + tr4[0].CMP, a0.y + tr4[1].CMP);                          \
    M = max3f(M, a0.z + tr4[2].CMP, a0.w + tr4[3].CMP);                       \
    M = max3f(M, a1.x + tr4[4].CMP, a1.y + tr4[5].CMP);                       \
    M = max3f(M, a1.z + tr4[6].CMP, a1.w + tr4[7].CMP);                       \
    M = max3f(M, a2.x + tr4[8].CMP, a2.y + tr4[9].CMP);                       \
    M = max3f(M, a2.z + tr4[10].CMP, a2.w + tr4[11].CMP);                     \
    M = max3f(M, a3.x + tr4[12].CMP, a3.y + tr4[13].CMP);                     \
    M = max3f(M, a3.z + tr4[14].CMP, a3.w + tr4[15].CMP);                     \
  }

// ---------------- Kernel A: forward max-plus scan (+ trans transpose) ----------------
// R3 structure. R10: alpha LDS reads issued FIRST in the loop body. R11 (this
// round): inner reduction rewritten around v_max3_f32 — 96 MAC instrs/step
// instead of 140 (2 cells per max3; no -inf inits; no p/q combine).
__global__ __launch_bounds__(1024, 4) void crf_fwd_kernel(
    float* __restrict__ seq, const float* __restrict__ trans,
    float* __restrict__ transT, int useT) {
  __shared__ float lds[64 * 65];
  const int bi = blockIdx.x;
  const int tid = threadIdx.x;

  if (bi < Bn) {
    float* sb = seq + (size_t)bi * (Tn * Cn);
    const int l = tid & 63;
    const int w = tid >> 6;     // wave 0..15
    const int c = l & 15;       // cp-chunk lane (reduction index)
    const int g = l >> 4;       // cc-group within wave
    const int ccb = w * 16 + g * 4;  // 4 consecutive cc
    const int cpb = c * 16;          // 16 consecutive cp
    float4 tr4[16];  // trans fragment (unified-file AGPR residency is free)
#pragma unroll
    for (int k = 0; k < 16; ++k)
      tr4[k] = *(const float4*)(trans + (size_t)(cpb + k) * Cn + ccb);

    float* ab0 = lds;        // 320 floats (padded)
    float* ab1 = lds + 320;
    if (tid < 64) *(float4*)(ab0 + apad(tid)) = ((const float4*)sb)[tid];
    const bool leader = (c == 0);
    const int woff = apad(w * 4 + g);
    float4 e4, pna;
    if (leader) e4 = *(const float4*)(sb + Cn + ccb);  // emissions[1]
    __syncthreads();

    for (int t = 1; t < Tn; ++t) {
      // 1) issue this step's alpha LDS reads immediately after the barrier
      const float* av = (t & 1) ? ab0 : ab1;
      float* aw = (t & 1) ? ab1 : ab0;
      const float* avc = av + c * 20;
      const float4 a0 = *(const float4*)(avc + 0);
      const float4 a1 = *(const float4*)(avc + 4);
      const float4 a2 = *(const float4*)(avc + 8);
      const float4 a3 = *(const float4*)(avc + 12);
      // 2) leader global traffic overlaps the LDS latency
      float4 pf;
      if (leader) {
        if (t > 1) *(float4*)(sb + (size_t)(t - 1) * Cn + ccb) = pna;
        const int tn = (t + 1 < Tn) ? (t + 1) : (Tn - 1);
        pf = *(const float4*)(sb + (size_t)tn * Cn + ccb);
      }
      // 3) MACs: 2 cells folded per v_max3_f32; 4 independent 8-deep chains
      float m0, m1, m2, m3;
      REDUCE_CC(m0, x)
      REDUCE_CC(m1, y)
      REDUCE_CC(m2, z)
      REDUCE_CC(m3, w)
      // rotate-reduce max across the 16 c-lanes of this DPP row (exact)
      m0 = fmaxf(m0, dpp_mov_f<0x128>(m0)); m1 = fmaxf(m1, dpp_mov_f<0x128>(m1));
      m2 = fmaxf(m2, dpp_mov_f<0x128>(m2)); m3 = fmaxf(m3, dpp_mov_f<0x128>(m3));
      m0 = fmaxf(m0, dpp_mov_f<0x124>(m0)); m1 = fmaxf(m1, dpp_mov_f<0x124>(m1));
      m2 = fmaxf(m2, dpp_mov_f<0x124>(m2)); m3 = fmaxf(m3, dpp_mov_f<0x124>(m3));
      m0 = fmaxf(m0, dpp_mov_f<0x122>(m0)); m1 = fmaxf(m1, dpp_mov_f<0x122>(m1));
      m2 = fmaxf(m2, dpp_mov_f<0x122>(m2)); m3 = fmaxf(m3, dpp_mov_f<0x122>(m3));
      m0 = fmaxf(m0, dpp_mov_f<0x121>(m0)); m1 = fmaxf(m1, dpp_mov_f<0x121>(m1));
      m2 = fmaxf(m2, dpp_mov_f<0x121>(m2)); m3 = fmaxf(m3, dpp_mov_f<0x121>(m3));
      if (leader) {
        float4 na;
        na.x = m0 + e4.x; na.y = m1 + e4.y; na.z = m2 + e4.z; na.w = m3 + e4.w;
        *(float4*)(aw + woff) = na;
        pna = na;
        e4 = pf;
      }
      __syncthreads();
    }
    if (leader) *(float4*)(sb + (size_t)(Tn - 1) * Cn + ccb) = pna;
  } else if (useT) {
    // 64x64-tile transpose of trans into transT, LDS-staged, +1-padded
    const int idx = bi - Bn;  // 0..15
    const int ti = idx >> 2, tj = idx & 3;
    const int tx = tid & 63, ty = tid >> 6;  // ty 0..15
#pragma unroll
    for (int q = 0; q < 4; ++q) {
      const int row = q * 16 + ty;
      lds[tx * 65 + row] = trans[(size_t)(ti * 64 + row) * Cn + tj * 64 + tx];
    }
    __syncthreads();
#pragma unroll
    for (int q = 0; q < 4; ++q) {
      const int row = q * 16 + ty;
      transT[(size_t)(tj * 64 + row) * Cn + ti * 64 + tx] = lds[row * 65 + tx];
    }
  }
}

// ---------------- bwd helpers ----------------
__device__ __forceinline__ float4 onehot4(int tg, int cp0) {
  float4 z;
  z.x = (tg == cp0 + 0) ? 1.0f : 0.0f; z.y = (tg == cp0 + 1) ? 1.0f : 0.0f;
  z.z = (tg == cp0 + 2) ? 1.0f : 0.0f; z.w = (tg == cp0 + 3) ? 1.0f : 0.0f;
  return z;
}

// Chain chunk: per step, the dependent row load hits the LDS transT cache for
// tag < TCROWS (~40cy) else L2 (~200cy). tag is SGPR-uniform -> scalar branch.
template<int K>
__device__ __forceinline__ int chain_chunk(
    const float* __restrict__ A, int* __restrict__ tags,
    const float* __restrict__ transT, const float* __restrict__ tc,
    int tag, int l) {
  const int cp0 = l * 4;
#pragma unroll
  for (int k = 0; k < K; ++k) {
    float4 tv;
    if (tag < TCROWS) {
      tv = *(const float4*)(tc + tag * Cn + cp0);
    } else {
      tv = *(const float4*)(transT + (size_t)tag * Cn + cp0);
    }
    const float4 ac = *(const float4*)(A + k * Cn + cp0);
    float v = ac.x + tv.x; int i = cp0;
    float vv; bool cnd;
    vv = ac.y + tv.y; cnd = vv > v; v = cnd ? vv : v; i = cnd ? cp0 + 1 : i;
    vv = ac.z + tv.z; cnd = vv > v; v = cnd ? vv : v; i = cnd ? cp0 + 2 : i;
    vv = ac.w + tv.w; cnd = vv > v; v = cnd ? vv : v; i = cnd ? cp0 + 3 : i;
    tag = argmax64_fast(v, i);
    if (l == 0) tags[k] = tag;
  }
  return tag;
}

// ---------------- Kernel B: producer-consumer backtrack + one-hot -------------
// Wave0: dependent chain. Waves1-2: alpha global->LDS ring (non-temporal).
// Wave3: one-hot stores (non-temporal). R10: 127 transT rows cached in LDS.
__global__ __launch_bounds__(256) void crf_bwd_kernel(
    const float* __restrict__ seq, const float* __restrict__ trans,
    const float* __restrict__ transT, float* __restrict__ out, int useT) {
  __shared__ float aL[2][16][Cn];     // 32 KB alpha ring
  __shared__ float tc[TCROWS * Cn];   // 127 KB transT row cache
  __shared__ int tagL[2][16];
  const int b = blockIdx.x;
  const int tid = threadIdx.x;
  const int wv = tid >> 6;
  const int l = tid & 63;
  const int cp0 = l * 4;
  const float* sb = seq + (size_t)b * (Tn * Cn);  // alpha trail
  float* ob = out + (size_t)b * (Tn * Cn);

  if (!useT) {
    if (wv == 0) {
      float4 a = *(const float4*)(sb + (size_t)(Tn - 1) * Cn + cp0);
      float v = a.x; int i = cp0; bool cnd;
      cnd = a.y > v; v = cnd ? a.y : v; i = cnd ? cp0 + 1 : i;
      cnd = a.z > v; v = cnd ? a.z : v; i = cnd ? cp0 + 2 : i;
      cnd = a.w > v; v = cnd ? a.w : v; i = cnd ? cp0 + 3 : i;
      int tag = argmax64_fast(v, i);
      *(float4*)(ob + (size_t)(Tn - 1) * Cn + cp0) = onehot4(tag, cp0);
      for (int t = Tn - 2; t >= 0; --t) {
        const float4 ac = *(const float4*)(sb + (size_t)t * Cn + cp0);
        float4 tv;
        tv.x = trans[(size_t)(cp0 + 0) * Cn + tag];
        tv.y = trans[(size_t)(cp0 + 1) * Cn + tag];
        tv.z = trans[(size_t)(cp0 + 2) * Cn + tag];
        tv.w = trans[(size_t)(cp0 + 3) * Cn + tag];
        float v2 = ac.x + tv.x; int i2 = cp0; float vv; bool c2;
        vv = ac.y + tv.y; c2 = vv > v2; v2 = c2 ? vv : v2; i2 = c2 ? cp0 + 1 : i2;
        vv = ac.z + tv.z; c2 = vv > v2; v2 = c2 ? vv : v2; i2 = c2 ? cp0 + 2 : i2;
        vv = ac.w + tv.w; c2 = vv > v2; v2 = c2 ? vv : v2; i2 = c2 ? cp0 + 3 : i2;
        tag = argmax64_fast(v2, i2);
        *(float4*)(ob + (size_t)t * Cn + cp0) = onehot4(tag, cp0);
      }
    }
    return;
  }

  // Preload the transT LDS cache: wave wv loads rows [32*wv, min(127, 32*wv+32))
  {
    const int r0 = wv * 32;
    const int r1 = (r0 + 32 < TCROWS) ? (r0 + 32) : TCROWS;
    for (int r = r0; r < r1; ++r)
      *(float4*)(&tc[r * Cn + cp0]) = *(const float4*)(transT + (size_t)r * Cn + cp0);
  }

  int tag = 0;
  if (wv == 0) {
    float4 a = *(const float4*)(sb + (size_t)(Tn - 1) * Cn + cp0);
    float v = a.x; int i = cp0; bool cnd;
    cnd = a.y > v; v = cnd ? a.y : v; i = cnd ? cp0 + 1 : i;
    cnd = a.z > v; v = cnd ? a.z : v; i = cnd ? cp0 + 2 : i;
    cnd = a.w > v; v = cnd ? a.w : v; i = cnd ? cp0 + 3 : i;
    tag = argmax64_fast(v, i);
    *(float4*)(ob + (size_t)(Tn - 1) * Cn + cp0) = onehot4(tag, cp0);
  } else if (wv <= 2) {
    const int s0 = (wv == 1) ? 0 : 8, s1 = (wv == 1) ? 8 : 15;
    for (int s = s0; s < s1; ++s)
      *(float4*)(&aL[0][s][cp0]) = nt_load4(sb + (size_t)(1022 - s) * Cn + cp0);
  }
  __syncthreads();

  int p = 0, t0 = 1022, K = 15, pt0 = 0, pK = 0;
  for (int ch = 0; ch < 64; ++ch) {
    const int nt0 = t0 - K;
    if (wv == 0) {
      if (ch == 0) tag = chain_chunk<15>(&aL[p][0][0], tagL[p], transT, tc, tag, l);
      else        tag = chain_chunk<16>(&aL[p][0][0], tagL[p], transT, tc, tag, l);
    } else if (wv <= 2) {
      if (ch < 63) {
        const int s0 = (wv == 1) ? 0 : 8, s1 = (wv == 1) ? 8 : 16;
        for (int s = s0; s < s1; ++s)
          *(float4*)(&aL[1 - p][s][cp0]) = nt_load4(sb + (size_t)(nt0 - s) * Cn + cp0);
      }
    } else {
      if (ch > 0) {
        for (int k = 0; k < pK; ++k)
          nt_store4(ob + (size_t)(pt0 - k) * Cn + cp0, onehot4(tagL[1 - p][k], cp0));
      }
    }
    __syncthreads();
    pt0 = t0; pK = K; t0 = nt0; K = 16; p ^= 1;
  }
  if (wv == 3) {
    for (int k = 0; k < 16; ++k)
      nt_store4(ob + (size_t)(15 - k) * Cn + cp0, onehot4(tagL[1][k], cp0));
  }
}

extern "C" void kernel_launch(void* const* d_in, const int* in_sizes, int n_in,
                              void* d_out, int out_size, void* d_ws, size_t ws_size,
                              hipStream_t stream) {
  float* seq = (float*)d_in[0];
  const float* trans = (const float*)d_in[1];
  float* out = (float*)d_out;
  float* transT = (float*)d_ws;
  const int useT = (ws_size >= (size_t)Cn * Cn * sizeof(float)) ? 1 : 0;

  crf_fwd_kernel<<<dim3(Bn + 16), dim3(1024), 0, stream>>>(seq, trans, transT, useT);
  crf_bwd_kernel<<<dim3(Bn), dim3(256), 0, stream>>>(seq, trans, transT, out, useT);
}

// Round 2
// 1255.030 us; speedup vs baseline: 1.0064x; 1.0000x over previous
//
#include <hip/hip_runtime.h>

#define Bn 64
#define Tn 1024
#define Cn 256
#define TCROWS 127  // transT rows cached in bwd LDS (127KB + 32KB ring + tags < 160KB)

// Native clang vector for nontemporal builtins (HIP float4 is a class type).
typedef float nv4 __attribute__((ext_vector_type(4)));
__device__ __forceinline__ float4 nt_load4(const float* p) {
  nv4 r = __builtin_nontemporal_load((const nv4*)p);
  return make_float4(r.x, r.y, r.z, r.w);
}
__device__ __forceinline__ void nt_store4(float* p, float4 v) {
  nv4 r = {v.x, v.y, v.z, v.w};
  __builtin_nontemporal_store(r, (nv4*)p);
}

// Single-instruction 3-input max (gfx9+). Exact: fp32 max is associative.
__device__ __forceinline__ float max3f(float a, float b, float c) {
  float d;
  asm("v_max3_f32 %0, %1, %2, %3" : "=v"(d) : "v"(a), "v"(b), "v"(c));
  return d;
}

// R12: barrier that waits ONLY on LDS (lgkmcnt), leaving global stores/loads
// in flight across the barrier. __syncthreads() would drain vmcnt(0) every
// step, serializing the alpha-writeback store ack + emission prefetch into
// the 1023-step critical path. The global traffic here is lane-private
// (each leader lane touches only its own 4 columns), so no cross-wave
// ordering through global memory is needed.
#define BAR_LGKM() asm volatile("s_waitcnt lgkmcnt(0)\n\ts_barrier" ::: "memory")

// ---------------- DPP helpers ----------------
template<int CTRL>
__device__ __forceinline__ float dpp_mov_f(float x) {
  return __int_as_float(__builtin_amdgcn_update_dpp(0, __float_as_int(x), CTRL, 0xF, 0xF, true));
}
template<int CTRL>
__device__ __forceinline__ void max_stage(float& v) {
  const float pv = __int_as_float(__builtin_amdgcn_update_dpp(
      (int)0xFF800000, __float_as_int(v), CTRL, 0xF, 0xF, false));
  v = fmaxf(v, pv);
}

// Fast 64-lane argmax (min index on ties). Matches jnp argmax tie-break.
__device__ __forceinline__ int argmax64_fast(float v, int i) {
  float mv = v;
  max_stage<0x111>(mv);  // row_shr:1
  max_stage<0x112>(mv);  // row_shr:2
  max_stage<0x114>(mv);  // row_shr:4
  max_stage<0x118>(mv);  // row_shr:8
  max_stage<0x142>(mv);  // row_bcast15
  max_stage<0x143>(mv);  // row_bcast31  -> lane 63 has global max
  const float smax = __int_as_float(__builtin_amdgcn_readlane(__float_as_int(mv), 63));
  const unsigned long long m = __ballot(v == smax);
  const int ln = __ffsll((unsigned long long)m) - 1;
  return __builtin_amdgcn_readlane(i, ln);
}

// Padded alpha LDS layout (R3-verified: conflicts 5.0e7 -> 512):
// chunk m at float offset (m>>2)*20 + (m&3)*4. Buffer = 320 floats.
__device__ __forceinline__ int apad(int m) { return (m >> 2) * 20 + (m & 3) * 4; }

// Reduce 16 cp cells into accumulator M for one cc component CMP.
// 16 v_add + 1 v_max + 7 v_max3 = 24 instrs. Chain depth 8; exact.
#define REDUCE_CC(M, CMP)                                                     \
  {                                                                           \
    M = fmaxf(a0.x + tr4[0].CMP, a0.y + tr4[1].CMP);                          \
    M = max3f(M, a0.z + tr4[2].CMP, a0.w + tr4[3].CMP);                       \
    M = max3f(M, a1.x + tr4[4].CMP, a1.y + tr4[5].CMP);                       \
    M = max3f(M, a1.z + tr4[6].CMP, a1.w + tr4[7].CMP);                       \
    M = max3f(M, a2.x + tr4[8].CMP, a2.y + tr4[9].CMP);                       \
    M = max3f(M, a2.z + tr4[10].CMP, a2.w + tr4[11].CMP);                     \
    M = max3f(M, a3.x + tr4[12].CMP, a3.y + tr4[13].CMP);                     \
    M = max3f(M, a3.z + tr4[14].CMP, a3.w + tr4[15].CMP);                     \
  }

// ---------------- Kernel A: forward max-plus scan (+ trans transpose) ----------------
// R3 structure. R10: alpha LDS reads issued FIRST in the loop body.
// R12: in-loop barrier waits lgkmcnt only — global alpha writeback + emission
// prefetch stay in flight across steps (counted-vmcnt idea, T4).
__global__ __launch_bounds__(1024, 4) void crf_fwd_kernel(
    float* __restrict__ seq, const float* __restrict__ trans,
    float* __restrict__ transT, int useT) {
  __shared__ float lds[64 * 65];
  const int bi = blockIdx.x;
  const int tid = threadIdx.x;

  if (bi < Bn) {
    float* sb = seq + (size_t)bi * (Tn * Cn);
    const int l = tid & 63;
    const int w = tid >> 6;     // wave 0..15
    const int c = l & 15;       // cp-chunk lane (reduction index)
    const int g = l >> 4;       // cc-group within wave
    const int ccb = w * 16 + g * 4;  // 4 consecutive cc
    const int cpb = c * 16;          // 16 consecutive cp
    float4 tr4[16];  // trans fragment (unified-file AGPR residency is free)
#pragma unroll
    for (int k = 0; k < 16; ++k)
      tr4[k] = *(const float4*)(trans + (size_t)(cpb + k) * Cn + ccb);

    float* ab0 = lds;        // 320 floats (padded)
    float* ab1 = lds + 320;
    if (tid < 64) *(float4*)(ab0 + apad(tid)) = ((const float4*)sb)[tid];
    const bool leader = (c == 0);
    const int woff = apad(w * 4 + g);
    float4 e4, pna;
    if (leader) e4 = *(const float4*)(sb + Cn + ccb);  // emissions[1]
    __syncthreads();

    for (int t = 1; t < Tn; ++t) {
      // 1) issue this step's alpha LDS reads immediately after the barrier
      const float* av = (t & 1) ? ab0 : ab1;
      float* aw = (t & 1) ? ab1 : ab0;
      const float* avc = av + c * 20;
      const float4 a0 = *(const float4*)(avc + 0);
      const float4 a1 = *(const float4*)(avc + 4);
      const float4 a2 = *(const float4*)(avc + 8);
      const float4 a3 = *(const float4*)(avc + 12);
      // 2) leader global traffic: lane-private; stays in flight across the
      //    relaxed barrier (pf consumed only next step -> latency hidden)
      float4 pf;
      if (leader) {
        if (t > 1) *(float4*)(sb + (size_t)(t - 1) * Cn + ccb) = pna;
        const int tn = (t + 1 < Tn) ? (t + 1) : (Tn - 1);
        pf = *(const float4*)(sb + (size_t)tn * Cn + ccb);
      }
      // 3) MACs: 2 cells folded per v_max3_f32; 4 independent 8-deep chains
      float m0, m1, m2, m3;
      REDUCE_CC(m0, x)
      REDUCE_CC(m1, y)
      REDUCE_CC(m2, z)
      REDUCE_CC(m3, w)
      // rotate-reduce max across the 16 c-lanes of this DPP row (exact)
      m0 = fmaxf(m0, dpp_mov_f<0x128>(m0)); m1 = fmaxf(m1, dpp_mov_f<0x128>(m1));
      m2 = fmaxf(m2, dpp_mov_f<0x128>(m2)); m3 = fmaxf(m3, dpp_mov_f<0x128>(m3));
      m0 = fmaxf(m0, dpp_mov_f<0x124>(m0)); m1 = fmaxf(m1, dpp_mov_f<0x124>(m1));
      m2 = fmaxf(m2, dpp_mov_f<0x124>(m2)); m3 = fmaxf(m3, dpp_mov_f<0x124>(m3));
      m0 = fmaxf(m0, dpp_mov_f<0x122>(m0)); m1 = fmaxf(m1, dpp_mov_f<0x122>(m1));
      m2 = fmaxf(m2, dpp_mov_f<0x122>(m2)); m3 = fmaxf(m3, dpp_mov_f<0x122>(m3));
      m0 = fmaxf(m0, dpp_mov_f<0x121>(m0)); m1 = fmaxf(m1, dpp_mov_f<0x121>(m1));
      m2 = fmaxf(m2, dpp_mov_f<0x121>(m2)); m3 = fmaxf(m3, dpp_mov_f<0x121>(m3));
      if (leader) {
        float4 na;
        na.x = m0 + e4.x; na.y = m1 + e4.y; na.z = m2 + e4.z; na.w = m3 + e4.w;
        *(float4*)(aw + woff) = na;
        pna = na;
        e4 = pf;
      }
      BAR_LGKM();  // LDS-ordered only; global ops remain outstanding
    }
    if (leader) *(float4*)(sb + (size_t)(Tn - 1) * Cn + ccb) = pna;
  } else if (useT) {
    // 64x64-tile transpose of trans into transT, LDS-staged, +1-padded
    const int idx = bi - Bn;  // 0..15
    const int ti = idx >> 2, tj = idx & 3;
    const int tx = tid & 63, ty = tid >> 6;  // ty 0..15
#pragma unroll
    for (int q = 0; q < 4; ++q) {
      const int row = q * 16 + ty;
      lds[tx * 65 + row] = trans[(size_t)(ti * 64 + row) * Cn + tj * 64 + tx];
    }
    __syncthreads();
#pragma unroll
    for (int q = 0; q < 4; ++q) {
      const int row = q * 16 + ty;
      transT[(size_t)(tj * 64 + row) * Cn + ti * 64 + tx] = lds[row * 65 + tx];
    }
  }
}

// ---------------- bwd helpers ----------------
__device__ __forceinline__ float4 onehot4(int tg, int cp0) {
  float4 z;
  z.x = (tg == cp0 + 0) ? 1.0f : 0.0f; z.y = (tg == cp0 + 1) ? 1.0f : 0.0f;
  z.z = (tg == cp0 + 2) ? 1.0f : 0.0f; z.w = (tg == cp0 + 3) ? 1.0f : 0.0f;
  return z;
}

// Chain chunk: per step, the dependent row load hits the LDS transT cache for
// tag < TCROWS (~40cy) else L2 (~200cy). tag is SGPR-uniform -> scalar branch.
template<int K>
__device__ __forceinline__ int chain_chunk(
    const float* __restrict__ A, int* __restrict__ tags,
    const float* __restrict__ transT, const float* __restrict__ tc,
    int tag, int l) {
  const int cp0 = l * 4;
#pragma unroll
  for (int k = 0; k < K; ++k) {
    float4 tv;
    if (tag < TCROWS) {
      tv = *(const float4*)(tc + tag * Cn + cp0);
    } else {
      tv = *(const float4*)(transT + (size_t)tag * Cn + cp0);
    }
    const float4 ac = *(const float4*)(A + k * Cn + cp0);
    float v = ac.x + tv.x; int i = cp0;
    float vv; bool cnd;
    vv = ac.y + tv.y; cnd = vv > v; v = cnd ? vv : v; i = cnd ? cp0 + 1 : i;
    vv = ac.z + tv.z; cnd = vv > v; v = cnd ? vv : v; i = cnd ? cp0 + 2 : i;
    vv = ac.w + tv.w; cnd = vv > v; v = cnd ? vv : v; i = cnd ? cp0 + 3 : i;
    tag = argmax64_fast(v, i);
    if (l == 0) tags[k] = tag;
  }
  return tag;
}

// ---------------- Kernel B: producer-consumer backtrack + one-hot -------------
// Wave0: dependent chain. Waves1-2: alpha global->LDS ring (non-temporal).
// Wave3: one-hot stores (non-temporal). R10: 127 transT rows cached in LDS.
__global__ __launch_bounds__(256) void crf_bwd_kernel(
    const float* __restrict__ seq, const float* __restrict__ trans,
    const float* __restrict__ transT, float* __restrict__ out, int useT) {
  __shared__ float aL[2][16][Cn];     // 32 KB alpha ring
  __shared__ float tc[TCROWS * Cn];   // 127 KB transT row cache
  __shared__ int tagL[2][16];
  const int b = blockIdx.x;
  const int tid = threadIdx.x;
  const int wv = tid >> 6;
  const int l = tid & 63;
  const int cp0 = l * 4;
  const float* sb = seq + (size_t)b * (Tn * Cn);  // alpha trail
  float* ob = out + (size_t)b * (Tn * Cn);

  if (!useT) {
    if (wv == 0) {
      float4 a = *(const float4*)(sb + (size_t)(Tn - 1) * Cn + cp0);
      float v = a.x; int i = cp0; bool cnd;
      cnd = a.y > v; v = cnd ? a.y : v; i = cnd ? cp0 + 1 : i;
      cnd = a.z > v; v = cnd ? a.z : v; i = cnd ? cp0 + 2 : i;
      cnd = a.w > v; v = cnd ? a.w : v; i = cnd ? cp0 + 3 : i;
      int tag = argmax64_fast(v, i);
      *(float4*)(ob + (size_t)(Tn - 1) * Cn + cp0) = onehot4(tag, cp0);
      for (int t = Tn - 2; t >= 0; --t) {
        const float4 ac = *(const float4*)(sb + (size_t)t * Cn + cp0);
        float4 tv;
        tv.x = trans[(size_t)(cp0 + 0) * Cn + tag];
        tv.y = trans[(size_t)(cp0 + 1) * Cn + tag];
        tv.z = trans[(size_t)(cp0 + 2) * Cn + tag];
        tv.w = trans[(size_t)(cp0 + 3) * Cn + tag];
        float v2 = ac.x + tv.x; int i2 = cp0; float vv; bool c2;
        vv = ac.y + tv.y; c2 = vv > v2; v2 = c2 ? vv : v2; i2 = c2 ? cp0 + 1 : i2;
        vv = ac.z + tv.z; c2 = vv > v2; v2 = c2 ? vv : v2; i2 = c2 ? cp0 + 2 : i2;
        vv = ac.w + tv.w; c2 = vv > v2; v2 = c2 ? vv : v2; i2 = c2 ? cp0 + 3 : i2;
        tag = argmax64_fast(v2, i2);
        *(float4*)(ob + (size_t)t * Cn + cp0) = onehot4(tag, cp0);
      }
    }
    return;
  }

  // Preload the transT LDS cache: wave wv loads rows [32*wv, min(127, 32*wv+32))
  {
    const int r0 = wv * 32;
    const int r1 = (r0 + 32 < TCROWS) ? (r0 + 32) : TCROWS;
    for (int r = r0; r < r1; ++r)
      *(float4*)(&tc[r * Cn + cp0]) = *(const float4*)(transT + (size_t)r * Cn + cp0);
  }

  int tag = 0;
  if (wv == 0) {
    float4 a = *(const float4*)(sb + (size_t)(Tn - 1) * Cn + cp0);
    float v = a.x; int i = cp0; bool cnd;
    cnd = a.y > v; v = cnd ? a.y : v; i = cnd ? cp0 + 1 : i;
    cnd = a.z > v; v = cnd ? a.z : v; i = cnd ? cp0 + 2 : i;
    cnd = a.w > v; v = cnd ? a.w : v; i = cnd ? cp0 + 3 : i;
    tag = argmax64_fast(v, i);
    *(float4*)(ob + (size_t)(Tn - 1) * Cn + cp0) = onehot4(tag, cp0);
  } else if (wv <= 2) {
    const int s0 = (wv == 1) ? 0 : 8, s1 = (wv == 1) ? 8 : 15;
    for (int s = s0; s < s1; ++s)
      *(float4*)(&aL[0][s][cp0]) = nt_load4(sb + (size_t)(1022 - s) * Cn + cp0);
  }
  __syncthreads();

  int p = 0, t0 = 1022, K = 15, pt0 = 0, pK = 0;
  for (int ch = 0; ch < 64; ++ch) {
    const int nt0 = t0 - K;
    if (wv == 0) {
      if (ch == 0) tag = chain_chunk<15>(&aL[p][0][0], tagL[p], transT, tc, tag, l);
      else        tag = chain_chunk<16>(&aL[p][0][0], tagL[p], transT, tc, tag, l);
    } else if (wv <= 2) {
      if (ch < 63) {
        const int s0 = (wv == 1) ? 0 : 8, s1 = (wv == 1) ? 8 : 16;
        for (int s = s0; s < s1; ++s)
          *(float4*)(&aL[1 - p][s][cp0]) = nt_load4(sb + (size_t)(nt0 - s) * Cn + cp0);
      }
    } else {
      if (ch > 0) {
        for (int k = 0; k < pK; ++k)
          nt_store4(ob + (size_t)(pt0 - k) * Cn + cp0, onehot4(tagL[1 - p][k], cp0));
      }
    }
    __syncthreads();
    pt0 = t0; pK = K; t0 = nt0; K = 16; p ^= 1;
  }
  if (wv == 3) {
    for (int k = 0; k < 16; ++k)
      nt_store4(ob + (size_t)(15 - k) * Cn + cp0, onehot4(tagL[1][k], cp0));
  }
}

extern "C" void kernel_launch(void* const* d_in, const int* in_sizes, int n_in,
                              void* d_out, int out_size, void* d_ws, size_t ws_size,
                              hipStream_t stream) {
  float* seq = (float*)d_in[0];
  const float* trans = (const float*)d_in[1];
  float* out = (float*)d_out;
  float* transT = (float*)d_ws;
  const int useT = (ws_size >= (size_t)Cn * Cn * sizeof(float)) ? 1 : 0;

  crf_fwd_kernel<<<dim3(Bn + 16), dim3(1024), 0, stream>>>(seq, trans, transT, useT);
  crf_bwd_kernel<<<dim3(Bn), dim3(256), 0, stream>>>(seq, trans, transT, out, useT);
}